// Round 5
// baseline (397.892 us; speedup 1.0000x reference)
//
#include <hip/hip_runtime.h>

#define TSTEPS 512
#define NP 7            // producer waves per consumer block
#define S  32           // ring slots (power of 2)
#define NCB 128         // consumer blocks (= BATCH)
#define LEAD 40         // prefetcher max lead, steps (40*4KB*16 blk/XCD = 2.5MB < 4MB L2)

typedef __bf16 bf16x8 __attribute__((ext_vector_type(8)));
typedef float f32x16 __attribute__((ext_vector_type(16)));
typedef unsigned int uint4v __attribute__((ext_vector_type(4)));

#if __has_builtin(__builtin_amdgcn_cvt_pk_bf16_f32)
__device__ __forceinline__ unsigned packbf(float lo, float hi) {
    return __builtin_bit_cast(unsigned, __builtin_amdgcn_cvt_pk_bf16_f32(lo, hi));
}
#else
__device__ __forceinline__ unsigned rne_(float f) {
    unsigned u = __float_as_uint(f);
    return u + 0x7fffu + ((u >> 16) & 1u);
}
__device__ __forceinline__ unsigned packbf(float lo, float hi) {
    return __builtin_amdgcn_perm(rne_(hi), rne_(lo), 0x07060302u);
}
#endif

__device__ __forceinline__ int ldf(const int* p) {
    return __hip_atomic_load(p, __ATOMIC_RELAXED, __HIP_MEMORY_SCOPE_WORKGROUP);
}
__device__ __forceinline__ void stf(int* p, int v) {
    __hip_atomic_store(p, v, __ATOMIC_RELAXED, __HIP_MEMORY_SCOPE_WORKGROUP);
}

// Blocks 0..127: one per batch. Wave 0 = consumer (sequential MFMA recurrence
// in C/D register space), waves 1..7 = producers (kappa-order global gather of
// x_t, +b, bf16 pack, into a 32-slot LDS ring).
// Blocks 128..255: L2-warming prefetchers. Block b+128 streams x[batch b]
// into its XCD's L2 ahead of block b's producers (b and b+128 share
// blockIdx%8, i.e. the same XCD under round-robin mapping). R4 analysis:
// 128 memory-active CUs at ~10 B/cyc/CU per-CU HBM ceiling -> 87+ us floor;
// prefetchers double the memory-engaged CUs. Pacing via device-scope progress
// word in d_ws; pure perf hint, correctness never depends on it (G16-safe).
//
// Recurrence (transposed space, u = h^T + b2^T):
//   u_{t+1} = (b+x_t)^T @ bf16(u_t) + b2^T   (b2^T as the MFMA C operand).
// C/D layout: col=lane&31, row=(reg&3)+8*(reg>>2)+4*(lane>>5).
// kappa(c,h,j)=c*16+4h+(j&3)+8*(j>>2) makes the B fragment the natural C/D
// register order -> recurrent state never crosses lanes.
// [Verified R2-R4: absmax 2.44e-4.]
__global__ void __launch_bounds__(64 * (NP + 1), 1)
minrnn_kernel(const float* __restrict__ x, const float* __restrict__ bvec,
              const float* __restrict__ b2vec, const float* __restrict__ h0,
              float* __restrict__ out, int* __restrict__ prog)
{
    const int bid = blockIdx.x;

    if (bid >= NCB) {
        // ---------------- prefetcher block ----------------
        const int bb   = bid - NCB;
        const int wave = threadIdx.x >> 6;
        const int l    = threadIdx.x & 63;
        const float4* xb = (const float4*)(x + (size_t)bb * TSTEPS * 1024);
        float4 acc = {0.f, 0.f, 0.f, 0.f};
        int pg = 0;
        for (int t = wave; t < TSTEPS; t += 8) {
            while (t > pg + LEAD) {
                int p = __hip_atomic_load(&prog[bb], __ATOMIC_RELAXED,
                                          __HIP_MEMORY_SCOPE_AGENT);
                pg = (p < 0 || p > TSTEPS) ? 0 : p;   // poison-tolerant (0xAA.. < 0)
                if (t <= pg + LEAD) break;
                __builtin_amdgcn_s_sleep(8);
            }
#pragma unroll
            for (int q = 0; q < 4; ++q) {
                float4 v = xb[t * 256 + q * 64 + l];
                acc.x += v.x; acc.y += v.y; acc.z += v.z; acc.w += v.w;
            }
        }
        // sink so the loads are not DCE'd (d_ws scratch, past the prog words)
        float* sink = (float*)(prog + 256);
        sink[(size_t)bid * 512 + threadIdx.x] = acc.x + acc.y + acc.z + acc.w;
        return;
    }

    // ---------------- worker block (consumer + producers) ----------------
    __shared__ unsigned ring[S * 512];   // 64 KB, slot base (t%S)*512, elem d*64+l
    __shared__ int flags[S];
    __shared__ int consumed;

    const int tid  = threadIdx.x;
    const int wave = tid >> 6;
    const int l    = tid & 63;
    const int col  = l & 31;
    const int half = l >> 5;
    const int bb   = bid;

    if (tid < S) flags[tid] = 0;
    if (tid == 0) consumed = -1;
    __syncthreads();

    if (wave == 0) {
        // ---------------- consumer ----------------
        float u[16];
        f32x16 cb2;
#pragma unroll
        for (int i = 0; i < 16; ++i) {
            const int row = (i & 3) + 8 * (i >> 2) + 4 * half;
            const float b2v = b2vec[col * 32 + row];
            cb2[i] = b2v;
            u[i] = h0[bb * 1024 + col * 32 + row] + b2v;
        }

        int flagn = ldf(&flags[0]);
        while (flagn != 1) flagn = ldf(&flags[0]);
        __threadfence_block();
        unsigned cur[8], nxt[8];
#pragma unroll
        for (int d = 0; d < 8; ++d) cur[d] = ring[d * 64 + l];
        flagn = ldf(&flags[1]);

        for (int t = 0; t < TSTEPS; ++t) {
            if (t < TSTEPS - 1) {
                const int want = t + 2;           // flag value for slot t+1
                while (flagn != want) flagn = ldf(&flags[(t + 1) & (S - 1)]);
                __threadfence_block();            // acquire
                const int sb = ((t + 1) & (S - 1)) << 9;
#pragma unroll
                for (int d = 0; d < 8; ++d) nxt[d] = ring[sb + d * 64 + l];
                if (t + 2 < TSTEPS) flagn = ldf(&flags[(t + 2) & (S - 1)]);
            }

            unsigned pb[8];
#pragma unroll
            for (int i = 0; i < 8; ++i) pb[i] = packbf(u[2 * i], u[2 * i + 1]);
            const bf16x8 B0 = __builtin_bit_cast(bf16x8, (uint4v){pb[0], pb[1], pb[2], pb[3]});
            const bf16x8 B1 = __builtin_bit_cast(bf16x8, (uint4v){pb[4], pb[5], pb[6], pb[7]});
            const bf16x8 A0 = __builtin_bit_cast(bf16x8, (uint4v){cur[0], cur[1], cur[2], cur[3]});
            const bf16x8 A1 = __builtin_bit_cast(bf16x8, (uint4v){cur[4], cur[5], cur[6], cur[7]});

            f32x16 acc = __builtin_amdgcn_mfma_f32_32x32x16_bf16(A0, B0, cb2, 0, 0, 0);
            acc        = __builtin_amdgcn_mfma_f32_32x32x16_bf16(A1, B1, acc, 0, 0, 0);
#pragma unroll
            for (int i = 0; i < 16; ++i) u[i] = acc[i];

            if (l == 0) {
                if ((t & 7) == 7) stf(&consumed, t);
                if ((t & 15) == 15)
                    __hip_atomic_store(&prog[bb], t, __ATOMIC_RELAXED,
                                       __HIP_MEMORY_SCOPE_AGENT);
            }
#pragma unroll
            for (int d = 0; d < 8; ++d) cur[d] = nxt[d];
        }

        // out = u - b2^T = g^T : lane holds g[row][col] -> out[col*32+row]
#pragma unroll
        for (int i = 0; i < 16; ++i) {
            const int row = (i & 3) + 8 * (i >> 2) + 4 * half;
            out[bb * 1024 + col * 32 + row] = u[i] - cb2[i];
        }
    } else {
        // ---------------- producers ----------------
        const int p = wave - 1;
        float bA[16];
        int off[16];
#pragma unroll
        for (int c = 0; c < 2; ++c)
#pragma unroll
            for (int j = 0; j < 8; ++j) {
                const int k = c * 16 + half * 4 + (j & 3) + 8 * (j >> 2); // kappa
                bA[c * 8 + j] = bvec[k * 32 + col];
                off[c * 8 + j] = c * 512 + half * 128 + (j >> 2) * 256 + (j & 3) * 32 + col;
            }
        const float* xb = x + (size_t)bb * TSTEPS * 1024;

        auto emit = [&](int t, const float* v) {
            while (ldf(&consumed) < t - 33) {}   // ring space (8-step publish lag safe)
            unsigned pa[8];
#pragma unroll
            for (int i = 0; i < 8; ++i)
                pa[i] = packbf(v[2 * i] + bA[2 * i], v[2 * i + 1] + bA[2 * i + 1]);
            const int sb = (t & (S - 1)) << 9;
#pragma unroll
            for (int d = 0; d < 8; ++d) ring[sb + d * 64 + l] = pa[d];
            __threadfence_block();               // release: data before flag
            if (l == 0) stf(&flags[t & (S - 1)], t + 1);
        };

        for (int t = p; t < TSTEPS; t += 2 * NP) {
            const int t2 = t + NP;
            float va[16], vb[16];
#pragma unroll
            for (int i = 0; i < 16; ++i) va[i] = xb[t * 1024 + off[i]];
            if (t2 < TSTEPS) {
#pragma unroll
                for (int i = 0; i < 16; ++i) vb[i] = xb[t2 * 1024 + off[i]];
            }
            __builtin_amdgcn_sched_barrier(0);   // pin load issue (R2 lesson)
            emit(t, va);
            if (t2 < TSTEPS) emit(t2, vb);
        }
    }
}

extern "C" void kernel_launch(void* const* d_in, const int* in_sizes, int n_in,
                              void* d_out, int out_size, void* d_ws, size_t ws_size,
                              hipStream_t stream)
{
    const float* x  = (const float*)d_in[0];
    const float* b  = (const float*)d_in[1];
    const float* b2 = (const float*)d_in[2];
    const float* h0 = (const float*)d_in[3];
    float* out = (float*)d_out;
    int* prog = (int*)d_ws;   // [0..127] progress words; sink area beyond
    minrnn_kernel<<<2 * NCB, 64 * (NP + 1), 0, stream>>>(x, b, b2, h0, out, prog);
}